// Round 4
// baseline (167.967 us; speedup 1.0000x reference)
//
#include <hip/hip_runtime.h>

typedef float v2f __attribute__((ext_vector_type(2)));

#define TPB    256
#define XPT    8                  // x points per thread
#define XPK    (XPT / 2)          // 4 packed x-pairs (v_pk_fma_f32)
#define XTILE  (TPB * XPT)        // 2048 x points per block
#define NPTS   8192
#define GX     (NPTS / XTILE)     // 4
#define GY     32                 // y chunks
#define YTILE  (NPTS / GY)        // 256, one LDS stage
#define NB     4
#define TOTPTS (NB * NPTS)        // 32768
#define NSLICE (2 * NB)           // 8 (dir,batch) slices
#define NREG   (GX * NSLICE)      // 32 finalize regions
#define WS2_FLOATS ((size_t)GY * NSLICE * NPTS)   // 2M floats = 8 MB

// ---------------------------------------------------------------------------
// ws layout:
//   [0, 8 MB)        per-(chunk, dir, b) partial mins of t' = 0.5|y|^2 - x.y
//                    (agent-scope stores/loads: per-XCD L2s are NOT coherent
//                    intra-kernel; plain st/ld across blocks would be stale)
//   ctrl[0..31]      region completion counters   (memset 0 — the ONLY init)
//   ctrl[32]         finalizer completion counter (memset 0)
//   partials[0..127] per-wave d-sums from 32 finalizers (written before read)
// ---------------------------------------------------------------------------

__global__ void __launch_bounds__(TPB) chamfer_fused(
        const float* __restrict__ T, const float* __restrict__ P,
        float* __restrict__ ws2, unsigned* __restrict__ ctrl,
        float* __restrict__ partials, float* __restrict__ out)
{
    __shared__ float4 sY[YTILE];     // (yx, yy, yz, 0.5*|y|^2), 4 KB
    __shared__ int sFlag;

    const int z   = blockIdx.z;
    const int dir = z >> 2;
    const int b   = z & 3;
    const float* Xb = (dir ? P : T) + (size_t)b * NPTS * 3;
    const float* Yb = (dir ? T : P) + (size_t)b * NPTS * 3;
    const int t  = threadIdx.x;
    const int x0 = blockIdx.x * XTILE;
    const int y0 = blockIdx.y * YTILE;

    {   // stage Y tile with precomputed hy = 0.5*|y|^2
        const float* yp = Yb + (size_t)(y0 + t) * 3;
        float yx = yp[0], yy = yp[1], yz = yp[2];
        sY[t] = make_float4(yx, yy, yz, 0.5f * (yx * yx + yy * yy + yz * yz));
    }

    // x points packed in pairs, pre-negated (neg folds into pk_fma for free)
    v2f nxx[XPK], nxy[XPK], nxz[XPK], m2[XPK];
#pragma unroll
    for (int k = 0; k < XPK; ++k) {
        const float* xp0 = Xb + (size_t)(x0 + (2 * k + 0) * TPB + t) * 3;
        const float* xp1 = Xb + (size_t)(x0 + (2 * k + 1) * TPB + t) * 3;
        nxx[k] = (v2f){-xp0[0], -xp1[0]};
        nxy[k] = (v2f){-xp0[1], -xp1[1]};
        nxz[k] = (v2f){-xp0[2], -xp1[2]};
        m2[k]  = (v2f){3.0e38f, 3.0e38f};
    }
    __syncthreads();

    // t' = hy - x.y : 3 v_pk_fma_f32 + 2 v_min_f32 per packed pair per y
    // = 5 issue slots / 2 pairs (was 8)
#pragma unroll 4
    for (int j = 0; j < YTILE; ++j) {
        float4 y = sY[j];
        v2f yx = {y.x, y.x}, yy = {y.y, y.y}, yz = {y.z, y.z}, yw = {y.w, y.w};
#pragma unroll
        for (int k = 0; k < XPK; ++k) {
            v2f acc = __builtin_elementwise_fma(nxx[k], yx, yw);
            acc = __builtin_elementwise_fma(nxy[k], yy, acc);
            acc = __builtin_elementwise_fma(nxz[k], yz, acc);
            m2[k] = __builtin_elementwise_min(m2[k], acc);
        }
    }

    // write this (chunk, z) slice — coherent (write-through) stores
    float* o = ws2 + ((size_t)blockIdx.y * NSLICE + z) * NPTS + x0 + t;
#pragma unroll
    for (int k = 0; k < XPK; ++k) {
        __hip_atomic_store(&o[(2 * k + 0) * TPB], m2[k].x,
                           __ATOMIC_RELAXED, __HIP_MEMORY_SCOPE_AGENT);
        __hip_atomic_store(&o[(2 * k + 1) * TPB], m2[k].y,
                           __ATOMIC_RELAXED, __HIP_MEMORY_SCOPE_AGENT);
    }
    __threadfence();

    if (t == 0) {
        unsigned old = __hip_atomic_fetch_add(&ctrl[z * GX + blockIdx.x], 1u,
                            __ATOMIC_ACQ_REL, __HIP_MEMORY_SCOPE_AGENT);
        sFlag = (old == GY - 1) ? 1 : 0;   // last chunk of this region
    }
    __syncthreads();
    if (!sFlag) return;

    // ---- finalize region (z, blockIdx.x): 2048 points, 8 per thread ----
    float wsum = 0.0f;
#pragma unroll
    for (int i = 0; i < XPT; ++i) {
        int x = x0 + i * TPB + t;
        const float* base = ws2 + (size_t)z * NPTS + x;
        float m = 3.0e38f;
#pragma unroll
        for (int c = 0; c < GY; ++c)
            m = fminf(m, __hip_atomic_load(&base[(size_t)c * NSLICE * NPTS],
                            __ATOMIC_RELAXED, __HIP_MEMORY_SCOPE_AGENT));
        const float* xp = Xb + (size_t)x * 3;
        float hx = 0.5f * (xp[0] * xp[0] + xp[1] * xp[1] + xp[2] * xp[2]);
        float d  = sqrtf(fmaxf(2.0f * (hx + m), 0.0f));
        if (dir) out[1 + b * NPTS + x] = d;   // mins_seeds
        wsum += d;
    }
#pragma unroll
    for (int off = 32; off > 0; off >>= 1)
        wsum += __shfl_down(wsum, off, 64);
    if ((t & 63) == 0)
        __hip_atomic_store(&partials[(z * GX + blockIdx.x) * 4 + (t >> 6)],
                           wsum, __ATOMIC_RELAXED, __HIP_MEMORY_SCOPE_AGENT);
    __threadfence();
    __syncthreads();

    if (t == 0) {
        unsigned old = __hip_atomic_fetch_add(&ctrl[NREG], 1u,
                            __ATOMIC_ACQ_REL, __HIP_MEMORY_SCOPE_AGENT);
        sFlag = (old == NREG - 1) ? 2 : 0;   // very last finalizer
    }
    __syncthreads();

    if (sFlag == 2 && t < 64) {   // one wave sums 128 per-wave partials
        float s = __hip_atomic_load(&partials[t],
                        __ATOMIC_RELAXED, __HIP_MEMORY_SCOPE_AGENT)
                + __hip_atomic_load(&partials[64 + t],
                        __ATOMIC_RELAXED, __HIP_MEMORY_SCOPE_AGENT);
#pragma unroll
        for (int off = 32; off > 0; off >>= 1)
            s += __shfl_down(s, off, 64);
        if (t == 0) out[0] = s * (1.0f / (float)TOTPTS);
    }
}

extern "C" void kernel_launch(void* const* d_in, const int* in_sizes, int n_in,
                              void* d_out, int out_size, void* d_ws, size_t ws_size,
                              hipStream_t stream) {
    const float* truep = (const float*)d_in[0];   // [4, 8192, 3] fp32
    const float* predp = (const float*)d_in[1];   // [4, 8192, 3] fp32
    float* out = (float*)d_out;                   // [1 + 32768] fp32

    float*    ws2      = (float*)d_ws;
    unsigned* ctrl     = (unsigned*)(ws2 + WS2_FLOATS);   // 33 u32
    float*    partials = (float*)(ctrl + NREG + 1);       // 128 floats

    // the ONLY init: 33 counter words -> 0
    hipMemsetAsync(ctrl, 0, (NREG + 1) * sizeof(unsigned), stream);

    dim3 grid(GX, GY, 2 * NB);    // (4, 32, 8) = 1024 blocks
    chamfer_fused<<<grid, TPB, 0, stream>>>(truep, predp, ws2, ctrl,
                                            partials, out);
}

// Round 5
// 102.008 us; speedup vs baseline: 1.6466x; 1.6466x over previous
//
#include <hip/hip_runtime.h>

typedef float v2f __attribute__((ext_vector_type(2)));

#define TPB    256
#define XPT    16                 // x points per thread
#define XPK    (XPT / 2)          // 8 packed x-pairs (v_pk_fma_f32)
#define XTILE  (TPB * XPT)        // 4096 x points per block
#define NPTS   8192
#define GX     (NPTS / XTILE)     // 2
#define GY     64                 // y chunks
#define YTILE  (NPTS / GY)        // 128 y points per block, one LDS stage
#define NB     4
#define TOTPTS (NB * NPTS)        // 32768
#define NPARTIAL ((2 * TOTPTS) / 64)   // 1024 per-wave partials

// ---------------------------------------------------------------------------
// ws layout:
//   keys[0 .. 2*TOTPTS)      flip-key u32 of min t' = 0.5|y|^2 - x.y
//                            (order-preserving map, combined via atomicMin;
//                            init = memset 0xFF = max key). 256 KB.
//   partials[0 .. 1024)      per-wave d-sums from finalize (write-then-read)
// Lesson from R4: fixed ~50us harness overhead, NOT per-dispatch — multi-
// kernel structure with plain cross-kernel visibility beats intra-kernel
// agent-scope coherence (which cost ~85us in fence/L2-writeback stalls).
// ---------------------------------------------------------------------------

// grid = (GX, GY, 2*NB) = (2, 64, 8) = 1024 blocks. blockIdx.z = dir*4 + b.
// Inner loop per y: 3 v_pk_fma_f32 + 2 v_min_f32 per packed x-pair.
__global__ void __launch_bounds__(TPB) nnmin_pk(
        const float* __restrict__ T, const float* __restrict__ P,
        unsigned* __restrict__ keys)
{
    __shared__ float4 sY[YTILE];   // (yx, yy, yz, 0.5*|y|^2), 2 KB

    const int z   = blockIdx.z;
    const int dir = z >> 2;
    const int b   = z & 3;
    const float* Xb = (dir ? P : T) + (size_t)b * NPTS * 3;
    const float* Yb = (dir ? T : P) + (size_t)b * NPTS * 3;
    const int t  = threadIdx.x;
    const int x0 = blockIdx.x * XTILE;
    const int y0 = blockIdx.y * YTILE;

    if (t < YTILE) {   // stage Y tile with precomputed hy = 0.5*|y|^2
        const float* yp = Yb + (size_t)(y0 + t) * 3;
        float yx = yp[0], yy = yp[1], yz = yp[2];
        sY[t] = make_float4(yx, yy, yz, 0.5f * (yx * yx + yy * yy + yz * yz));
    }

    // x points packed in pairs, pre-negated (folds the subtraction for free)
    v2f nxx[XPK], nxy[XPK], nxz[XPK], m2[XPK];
#pragma unroll
    for (int k = 0; k < XPK; ++k) {
        const float* xp0 = Xb + (size_t)(x0 + (2 * k + 0) * TPB + t) * 3;
        const float* xp1 = Xb + (size_t)(x0 + (2 * k + 1) * TPB + t) * 3;
        nxx[k] = (v2f){-xp0[0], -xp1[0]};
        nxy[k] = (v2f){-xp0[1], -xp1[1]};
        nxz[k] = (v2f){-xp0[2], -xp1[2]};
        m2[k]  = (v2f){3.0e38f, 3.0e38f};
    }
    __syncthreads();

    // t' = hy - x.y  (hx added in finalize; monotone in d for fixed x)
#pragma unroll 4
    for (int j = 0; j < YTILE; ++j) {
        float4 y = sY[j];
        v2f yx = {y.x, y.x}, yy = {y.y, y.y}, yz = {y.z, y.z}, yw = {y.w, y.w};
#pragma unroll
        for (int k = 0; k < XPK; ++k) {
            v2f acc = __builtin_elementwise_fma(nxx[k], yx, yw);
            acc = __builtin_elementwise_fma(nxy[k], yy, acc);
            acc = __builtin_elementwise_fma(nxz[k], yz, acc);
            m2[k] = __builtin_elementwise_min(m2[k], acc);
        }
    }

    // combine across the 64 y-chunks: atomicMin on order-preserving u32 key
    unsigned* o = keys + (size_t)dir * TOTPTS + (size_t)b * NPTS + x0 + t;
#pragma unroll
    for (int k = 0; k < XPK; ++k) {
        unsigned b0 = __float_as_uint(m2[k].x);
        unsigned b1 = __float_as_uint(m2[k].y);
        unsigned k0 = b0 ^ ((b0 & 0x80000000u) ? 0xFFFFFFFFu : 0x80000000u);
        unsigned k1 = b1 ^ ((b1 & 0x80000000u) ? 0xFFFFFFFFu : 0x80000000u);
        atomicMin(&o[(2 * k + 0) * TPB], k0);
        atomicMin(&o[(2 * k + 1) * TPB], k1);
    }
}

// Decode key, add hx, sqrt; write mins_seeds; per-wave partial sums.
__global__ void __launch_bounds__(TPB) finalize_kernel(
        const unsigned* __restrict__ keys,
        const float* __restrict__ T, const float* __restrict__ P,
        float* __restrict__ out, float* __restrict__ partials)
{
    int i   = blockIdx.x * TPB + threadIdx.x;   // 0 .. 2*TOTPTS-1
    int dir = (i >= TOTPTS) ? 1 : 0;            // uniform per block
    int idx = i - dir * TOTPTS;
    int b   = idx >> 13;                        // / NPTS
    int x   = idx & (NPTS - 1);

    unsigned k  = keys[i];
    unsigned bb = (k & 0x80000000u) ? (k ^ 0x80000000u) : ~k;
    float m = __uint_as_float(bb);

    const float* xp = (dir ? P : T) + ((size_t)b * NPTS + x) * 3;
    float a0 = xp[0], a1 = xp[1], a2 = xp[2];
    float hx = 0.5f * (a0 * a0 + a1 * a1 + a2 * a2);
    float d  = sqrtf(fmaxf(2.0f * (hx + m), 0.0f));
    if (dir) out[1 + idx] = d;                  // mins_seeds

#pragma unroll
    for (int off = 32; off > 0; off >>= 1)
        d += __shfl_down(d, off, 64);
    if ((threadIdx.x & 63) == 0) partials[i >> 6] = d;  // plain store
}

// Single-wave final reduction of 1024 per-wave partials.
__global__ void scalar_kernel(const float* __restrict__ partials,
                              float* __restrict__ out) {
    int t = threadIdx.x;                        // 64 threads
    float s = 0.0f;
#pragma unroll
    for (int k = 0; k < NPARTIAL / 64; ++k)     // 16 partials per lane
        s += partials[t * (NPARTIAL / 64) + k];
#pragma unroll
    for (int off = 32; off > 0; off >>= 1)
        s += __shfl_down(s, off, 64);
    if (t == 0) out[0] = s * (1.0f / (float)TOTPTS);
}

extern "C" void kernel_launch(void* const* d_in, const int* in_sizes, int n_in,
                              void* d_out, int out_size, void* d_ws, size_t ws_size,
                              hipStream_t stream) {
    const float* truep = (const float*)d_in[0];   // [4, 8192, 3] fp32
    const float* predp = (const float*)d_in[1];   // [4, 8192, 3] fp32
    float* out = (float*)d_out;                   // [1 + 32768] fp32

    unsigned* keys     = (unsigned*)d_ws;                 // 2*TOTPTS u32
    float*    partials = (float*)(keys + 2 * TOTPTS);     // 1024 floats

    // 0xFFFFFFFF = max flip-key: valid floor for atomicMin. 256 KB.
    hipMemsetAsync(keys, 0xFF, (size_t)2 * TOTPTS * 4, stream);

    dim3 grid(GX, GY, 2 * NB);                    // (2, 64, 8) = 1024 blocks
    nnmin_pk<<<grid, TPB, 0, stream>>>(truep, predp, keys);

    finalize_kernel<<<(2 * TOTPTS) / TPB, TPB, 0, stream>>>(
        keys, truep, predp, out, partials);
    scalar_kernel<<<1, 64, 0, stream>>>(partials, out);
}